// Round 2
// baseline (403.399 us; speedup 1.0000x reference)
//
#include <hip/hip_runtime.h>
#include <stdint.h>

// FeatureAttention: N=8192, D=512, U=256, fp32 in/out.
// Q=xWq, K=xWk, V=xWv; out = softmax(QK^T/16) V Wo
// bf16 MFMA (16x16x32), fp32 accum, flash attention with KV-split (dynamic 8/4/2).
// Fragment layouts (verified m89/m92/m97):
//   A-frag: lane l holds A[l&15][8*(l>>4)+e]
//   B-frag: lane l holds B[8*(l>>4)+e][l&15]
//   C/D:    reg i  holds C[(l>>4)*4+i][l&15]

#define N_ 8192
#define D_ 512
#define U_ 256

typedef __attribute__((ext_vector_type(8))) short short8;
typedef __attribute__((ext_vector_type(4))) float f32x4;
typedef __attribute__((ext_vector_type(4))) unsigned int u32x4;
typedef __attribute__((ext_vector_type(2))) unsigned int u32x2;

static __device__ __forceinline__ unsigned short f2bf(float f) {
    union { float f; unsigned int u; } c; c.f = f;
    unsigned int u = c.u;
    u += 0x7FFFu + ((u >> 16) & 1u);   // RNE
    return (unsigned short)(u >> 16);
}

// ---------------- kernel 0: weight convert + transpose ----------------
__global__ void k_convert(const float* __restrict__ Wq, const float* __restrict__ Wk,
                          const float* __restrict__ Wv, const float* __restrict__ Wo,
                          unsigned short* __restrict__ Wt, unsigned short* __restrict__ Wot) {
    int idx = blockIdx.x * 256 + threadIdx.x;
    const int nWt = 768 * 512;
    if (idx < nWt) {
        int j = idx >> 9, d = idx & 511;
        int which = j >> 8, u = j & 255;
        const float* W = (which == 0) ? Wq : ((which == 1) ? Wk : Wv);
        Wt[idx] = f2bf(W[d * 256 + u]);
    } else {
        int i2 = idx - nWt;
        if (i2 < 512 * 256) {
            int jj = i2 >> 8, u = i2 & 255;
            Wot[i2] = f2bf(Wo[u * 512 + jj]);
        }
    }
}

// ---------------- kernel 1: QKV = x @ [Wq|Wk|Wv] ----------------
__global__ __launch_bounds__(256) void k_qkv(const float* __restrict__ x,
        const unsigned short* __restrict__ Wt,
        unsigned short* __restrict__ Q, unsigned short* __restrict__ K,
        unsigned short* __restrict__ Vt) {
    const int w  = threadIdx.x >> 6;
    const int l  = threadIdx.x & 63;
    const int lg = l >> 4, ln = l & 15;
    const int i0 = blockIdx.x * 64 + w * 16;
    const int j0 = blockIdx.y * 64;

    f32x4 acc[4] = {};
#pragma unroll 4
    for (int kc = 0; kc < 16; ++kc) {
        const float* ap = x + (size_t)(i0 + ln) * D_ + kc * 32 + 8 * lg;
        f32x4 a0 = *(const f32x4*)(ap);
        f32x4 a1 = *(const f32x4*)(ap + 4);
        short8 afr;
        afr[0] = (short)f2bf(a0[0]); afr[1] = (short)f2bf(a0[1]);
        afr[2] = (short)f2bf(a0[2]); afr[3] = (short)f2bf(a0[3]);
        afr[4] = (short)f2bf(a1[0]); afr[5] = (short)f2bf(a1[1]);
        afr[6] = (short)f2bf(a1[2]); afr[7] = (short)f2bf(a1[3]);
#pragma unroll
        for (int t = 0; t < 4; ++t) {
            const unsigned short* bp = Wt + (size_t)(j0 + 16 * t + ln) * D_ + kc * 32 + 8 * lg;
            short8 bfr = *(const short8*)bp;
            acc[t] = __builtin_amdgcn_mfma_f32_16x16x32_bf16(afr, bfr, acc[t], 0, 0, 0);
        }
    }
#pragma unroll
    for (int t = 0; t < 4; ++t) {
        int j = j0 + 16 * t + ln;
#pragma unroll
        for (int i = 0; i < 4; ++i) {
            int row = i0 + lg * 4 + i;
            unsigned short v = f2bf(acc[t][i]);
            if (j < 256)        Q[(size_t)row * U_ + j] = v;
            else if (j < 512)   K[(size_t)row * U_ + (j - 256)] = v;
            else                Vt[(size_t)(j - 512) * N_ + row] = v;
        }
    }
}

// ---------------- kernel 2: flash attention partials ----------------
// grid (128, nsplit): blockIdx.x -> 64 Q rows (4 waves x 16), blockIdx.y -> KV slice.
__global__ __launch_bounds__(256) void k_attn(const unsigned short* __restrict__ Q,
        const unsigned short* __restrict__ K, const unsigned short* __restrict__ Vt,
        float* __restrict__ Opart, float* __restrict__ ml, int jlen) {
    __shared__ __align__(16) char ldsK[16384];   // [32 rows][512 B], byte ^= (row&7)<<4
    __shared__ __align__(16) char ldsV[16384];   // [256 u][64 B], chunk ^= (u>>1)&3
    __shared__ __align__(16) char ldsP[4096];    // per-wave [16 rows][64 B], chunk ^= (row>>1)&3

    const int tid = threadIdx.x;
    const int w = tid >> 6, l = tid & 63, lg = l >> 4, ln = l & 15;
    const int q0 = blockIdx.x * 64 + w * 16;
    const int sp = blockIdx.y;
    const int jbase = sp * jlen;
    const float scale = 0.0625f;

    // Q fragments for this wave's 16 rows (U=256 -> 8 k-chunks)
    short8 qf[8];
#pragma unroll
    for (int kc = 0; kc < 8; ++kc)
        qf[kc] = *(const short8*)(Q + (size_t)(q0 + ln) * U_ + kc * 32 + 8 * lg);

    f32x4 acc[16] = {};
    float mrun[4], lrun[4];
#pragma unroll
    for (int i = 0; i < 4; ++i) { mrun[i] = -3.0e38f; lrun[i] = 0.f; }

    for (int it = 0; it < jlen / 32; ++it) {
        const int j0 = jbase + it * 32;
        __syncthreads();
        // ---- stage K tile
        {
            const char* gK = (const char*)K + (size_t)j0 * 512;
#pragma unroll
            for (int r = 0; r < 4; ++r) {
                int o = (r * 256 + tid) * 16;
                u32x4 v = *(const u32x4*)(gK + o);
                int row = o >> 9;
                *(u32x4*)(ldsK + (o ^ ((row & 7) << 4))) = v;
            }
            const char* gV = (const char*)Vt + (size_t)j0 * 2;
#pragma unroll
            for (int r = 0; r < 4; ++r) {
                int o = (r * 256 + tid) * 16;
                int u = o >> 6, col = o & 63;
                u32x4 v = *(const u32x4*)(gV + (size_t)u * (N_ * 2) + col);
                int sw = (u * 64) | ((((col >> 4) ^ ((u >> 1) & 3)) << 4));
                *(u32x4*)(ldsV + sw) = v;
            }
        }
        __syncthreads();

        // ---- S = Q K^T : two 16x16 tiles (cols j0..+15, j0+16..+31)
        f32x4 s0 = {}, s1 = {};
#pragma unroll
        for (int kc = 0; kc < 8; ++kc) {
            int colb = kc * 64 + lg * 16;
            int r0 = ln, r1 = 16 + ln;
            short8 b0 = *(const short8*)(ldsK + r0 * 512 + (colb ^ ((r0 & 7) << 4)));
            short8 b1 = *(const short8*)(ldsK + r1 * 512 + (colb ^ ((r1 & 7) << 4)));
            s0 = __builtin_amdgcn_mfma_f32_16x16x32_bf16(qf[kc], b0, s0, 0, 0, 0);
            s1 = __builtin_amdgcn_mfma_f32_16x16x32_bf16(qf[kc], b1, s1, 0, 0, 0);
        }

        // ---- online softmax; exact skip when running max doesn't grow
        float mxv[4];
        int needf = 0;
#pragma unroll
        for (int i = 0; i < 4; ++i) {
            s0[i] *= scale; s1[i] *= scale;
            float mx = fmaxf(s0[i], s1[i]);
#pragma unroll
            for (int off = 1; off < 16; off <<= 1)
                mx = fmaxf(mx, __shfl_xor(mx, off, 64));
            mxv[i] = mx;
            needf |= (mx > mrun[i]);
        }
        float p0[4], p1[4];
        if (__any(needf)) {
            float alpha[4];
#pragma unroll
            for (int i = 0; i < 4; ++i) {
                float mn = fmaxf(mrun[i], mxv[i]);
                float al = __expf(mrun[i] - mn);
                float e0 = __expf(s0[i] - mn), e1 = __expf(s1[i] - mn);
                float rs = e0 + e1;
#pragma unroll
                for (int off = 1; off < 16; off <<= 1)
                    rs += __shfl_xor(rs, off, 64);
                lrun[i] = lrun[i] * al + rs;
                mrun[i] = mn;
                alpha[i] = al; p0[i] = e0; p1[i] = e1;
            }
#pragma unroll
            for (int t = 0; t < 16; ++t)
#pragma unroll
                for (int i = 0; i < 4; ++i) acc[t][i] *= alpha[i];
        } else {
#pragma unroll
            for (int i = 0; i < 4; ++i) {
                float e0 = __expf(s0[i] - mrun[i]), e1 = __expf(s1[i] - mrun[i]);
                float rs = e0 + e1;
#pragma unroll
                for (int off = 1; off < 16; off <<= 1)
                    rs += __shfl_xor(rs, off, 64);
                lrun[i] += rs;
                p0[i] = e0; p1[i] = e1;
            }
        }

        // ---- P: C-layout -> A-layout via per-wave swizzled LDS tile
        {
            char* pb = ldsP + w * 1024;
#pragma unroll
            for (int i = 0; i < 4; ++i) {
                int row = lg * 4 + i;
                int swr = (row >> 1) & 3;
                int c0 = ln, c1 = 16 + ln;
                *(short*)(pb + row * 64 + ((((c0 >> 3) ^ swr) << 4) | ((c0 & 7) << 1))) = (short)f2bf(p0[i]);
                *(short*)(pb + row * 64 + ((((c1 >> 3) ^ swr) << 4) | ((c1 & 7) << 1))) = (short)f2bf(p1[i]);
            }
        }
        asm volatile("s_waitcnt lgkmcnt(0)" ::: "memory");
        __builtin_amdgcn_sched_barrier(0);
        short8 pa = *(const short8*)(ldsP + w * 1024 + ln * 64 + ((lg ^ ((ln >> 1) & 3)) << 4));

        // ---- O += P @ V  (16 u-tiles)
#pragma unroll
        for (int t = 0; t < 16; ++t) {
            int u = t * 16 + ln;
            short8 bv = *(const short8*)(ldsV + u * 64 + ((lg ^ ((u >> 1) & 3)) << 4));
            acc[t] = __builtin_amdgcn_mfma_f32_16x16x32_bf16(pa, bv, acc[t], 0, 0, 0);
        }
    }

    // ---- write partials
    float* Op = Opart + (size_t)sp * N_ * U_;
#pragma unroll
    for (int t = 0; t < 16; ++t) {
        int u = t * 16 + ln;
#pragma unroll
        for (int i = 0; i < 4; ++i) {
            int row = q0 + lg * 4 + i;
            Op[(size_t)row * U_ + u] = acc[t][i];
        }
    }
    if (ln == 0) {
#pragma unroll
        for (int i = 0; i < 4; ++i) {
            int row = q0 + lg * 4 + i;
            ml[(size_t)sp * 2 * N_ + row]      = mrun[i];
            ml[(size_t)sp * 2 * N_ + N_ + row] = lrun[i];
        }
    }
}

// ---------------- kernel 3: combine nsplit KV-splits -> PV bf16 ----------------
__global__ void k_combine(const float* __restrict__ Opart, const float* __restrict__ ml,
                          unsigned short* __restrict__ PV, int nsplit) {
    int idx = blockIdx.x * 256 + threadIdx.x;      // one thread = 4 u's of one row
    int row = idx >> 6;
    int u4  = (idx & 63) * 4;
    float m = -3.0e38f;
    for (int sp = 0; sp < nsplit; ++sp)
        m = fmaxf(m, ml[(size_t)sp * 2 * N_ + row]);
    float a0 = 0.f, a1 = 0.f, a2 = 0.f, a3 = 0.f, lsum = 0.f;
    for (int sp = 0; sp < nsplit; ++sp) {
        float ms = ml[(size_t)sp * 2 * N_ + row];
        float ls = ml[(size_t)sp * 2 * N_ + N_ + row];
        float a = __expf(ms - m);
        lsum += ls * a;
        f32x4 o = *(const f32x4*)(Opart + (size_t)sp * N_ * U_ + (size_t)row * U_ + u4);
        a0 += o[0] * a; a1 += o[1] * a; a2 += o[2] * a; a3 += o[3] * a;
    }
    float inv = 1.0f / lsum;
    unsigned int lo = (unsigned int)f2bf(a0 * inv) | ((unsigned int)f2bf(a1 * inv) << 16);
    unsigned int hi = (unsigned int)f2bf(a2 * inv) | ((unsigned int)f2bf(a3 * inv) << 16);
    u32x2 pk; pk[0] = lo; pk[1] = hi;
    *(u32x2*)(PV + (size_t)row * U_ + u4) = pk;
}

// ---------------- kernel 4: out = PV @ Wo ----------------
__global__ __launch_bounds__(256) void k_out(const unsigned short* __restrict__ PV,
        const unsigned short* __restrict__ Wot, float* __restrict__ out) {
    const int w = threadIdx.x >> 6, l = threadIdx.x & 63;
    const int lg = l >> 4, ln = l & 15;
    const int i0 = blockIdx.x * 64 + w * 16;
    const int j0 = blockIdx.y * 64;
    f32x4 acc[4] = {};
#pragma unroll
    for (int kc = 0; kc < 8; ++kc) {
        short8 afr = *(const short8*)(PV + (size_t)(i0 + ln) * U_ + kc * 32 + 8 * lg);
#pragma unroll
        for (int t = 0; t < 4; ++t) {
            short8 bfr = *(const short8*)(Wot + (size_t)(j0 + 16 * t + ln) * U_ + kc * 32 + 8 * lg);
            acc[t] = __builtin_amdgcn_mfma_f32_16x16x32_bf16(afr, bfr, acc[t], 0, 0, 0);
        }
    }
#pragma unroll
    for (int t = 0; t < 4; ++t) {
        int j = j0 + 16 * t + ln;
#pragma unroll
        for (int i = 0; i < 4; ++i) {
            int row = i0 + lg * 4 + i;
            out[(size_t)row * D_ + j] = acc[t][i];
        }
    }
}

// ---------------- launch ----------------
extern "C" void kernel_launch(void* const* d_in, const int* in_sizes, int n_in,
                              void* d_out, int out_size, void* d_ws, size_t ws_size,
                              hipStream_t stream) {
    const float* x  = (const float*)d_in[0];
    const float* Wq = (const float*)d_in[1];
    const float* Wk = (const float*)d_in[2];
    const float* Wv = (const float*)d_in[3];
    const float* Wo = (const float*)d_in[4];
    float* out = (float*)d_out;

    char* ws = (char*)d_ws;
    unsigned short* Wt   = (unsigned short*)(ws);                 //  768*512*2
    unsigned short* Wot  = (unsigned short*)(ws + 786432);        //  512*256*2
    unsigned short* Q    = (unsigned short*)(ws + 1048576);       // 4 MiB
    unsigned short* K    = (unsigned short*)(ws + 5242880);       // 4 MiB
    unsigned short* Vt   = (unsigned short*)(ws + 9437184);       // 4 MiB (transposed)
    unsigned short* PV   = (unsigned short*)(ws + 13631488);      // 4 MiB
    const size_t obase = 17825792;
    const size_t oeach = (size_t)N_ * U_ * 4;                     // 8 MiB per split
    const size_t mleach = (size_t)2 * N_ * 4;

    int nsplit = 2;
    if (ws_size >= obase + 8 * (oeach + mleach)) nsplit = 8;
    else if (ws_size >= obase + 4 * (oeach + mleach)) nsplit = 4;

    float* Opart = (float*)(ws + obase);
    float* mlp   = (float*)(ws + obase + (size_t)nsplit * oeach);
    (void)in_sizes; (void)n_in; (void)out_size;

    k_convert<<<2048, 256, 0, stream>>>(Wq, Wk, Wv, Wo, Wt, Wot);
    k_qkv<<<dim3(128, 12), 256, 0, stream>>>(x, Wt, Q, K, Vt);
    k_attn<<<dim3(128, nsplit), 256, 0, stream>>>(Q, K, Vt, Opart, mlp, N_ / nsplit);
    k_combine<<<2048, 256, 0, stream>>>(Opart, mlp, PV, nsplit);
    k_out<<<dim3(128, 8), 256, 0, stream>>>(PV, Wot, out);
}

// Round 3
// 291.919 us; speedup vs baseline: 1.3819x; 1.3819x over previous
//
#include <hip/hip_runtime.h>
#include <stdint.h>

// FeatureAttention: N=8192, D=512, U=256, fp32 in/out.
// Q=xWq/16, K=xWk, V=xWv; out = softmax(QK^T) V Wo   (scale folded into Wq)
// bf16 MFMA 16x16x32, fp32 accum, flash attention, KV-split=8.
// Fragment layouts (verified m89/m92/m97):
//   A-frag: lane l holds A[l&15][8*(l>>4)+e]
//   B-frag: lane l holds B[8*(l>>4)+e][l&15]
//   C/D:    reg i  holds C[(l>>4)*4+i][l&15]

#define N_ 8192
#define D_ 512
#define U_ 256

typedef __attribute__((ext_vector_type(8))) short short8;
typedef __attribute__((ext_vector_type(4))) float f32x4;
typedef __attribute__((ext_vector_type(4))) unsigned int u32x4;
typedef __attribute__((ext_vector_type(2))) unsigned int u32x2;

static __device__ __forceinline__ unsigned short f2bf(float f) {
    union { float f; unsigned int u; } c; c.f = f;
    unsigned int u = c.u;
    u += 0x7FFFu + ((u >> 16) & 1u);   // RNE
    return (unsigned short)(u >> 16);
}
static __device__ __forceinline__ float bf2f(unsigned short h) {
    union { unsigned int u; float f; } c; c.u = ((unsigned int)h) << 16;
    return c.f;
}

// ---------------- kernel 0: weight convert (+scale fold) + x->bf16 ----------------
__global__ void k_convert(const float* __restrict__ x, const float* __restrict__ Wq,
                          const float* __restrict__ Wk, const float* __restrict__ Wv,
                          const float* __restrict__ Wo,
                          unsigned short* __restrict__ Wt, unsigned short* __restrict__ Wot,
                          unsigned short* __restrict__ xb) {
    int idx = blockIdx.x * 256 + threadIdx.x;
    const int nWt = 768 * 512;          // 393216
    const int nWot = 512 * 256;         // 131072
    if (idx < nWt) {
        int j = idx >> 9, d = idx & 511;
        int which = j >> 8, u = j & 255;
        const float* W = (which == 0) ? Wq : ((which == 1) ? Wk : Wv);
        float v = W[d * 256 + u];
        if (which == 0) v *= 0.0625f;   // fold 1/sqrt(U): exact (power of 2)
        Wt[idx] = f2bf(v);
    } else if (idx < nWt + nWot) {
        int i2 = idx - nWt;
        int jj = i2 >> 8, u = i2 & 255;
        Wot[i2] = f2bf(Wo[u * 512 + jj]);
    } else {
        int i3 = idx - (nWt + nWot);
        if (i3 < N_ * D_) xb[i3] = f2bf(x[i3]);
    }
}

// ---------------- kernel 1: QKV = xb @ [Wq|Wk|Wv], 64x128 tiles ----------------
__global__ __launch_bounds__(256) void k_qkv(const unsigned short* __restrict__ xb,
        const unsigned short* __restrict__ Wt,
        unsigned short* __restrict__ Q, unsigned short* __restrict__ K,
        unsigned short* __restrict__ Vt) {
    __shared__ short ldsT[128][72];     // V transpose staging (pad 72 vs 64)
    const int w  = threadIdx.x >> 6;
    const int l  = threadIdx.x & 63;
    const int lg = l >> 4, ln = l & 15;
    const int i0 = blockIdx.x * 64 + w * 16;
    const int j0 = blockIdx.y * 128;

    f32x4 acc[8] = {};
#pragma unroll 2
    for (int kc = 0; kc < 16; ++kc) {
        short8 afr = *(const short8*)(xb + (size_t)(i0 + ln) * D_ + kc * 32 + 8 * lg);
#pragma unroll
        for (int t = 0; t < 8; ++t) {
            short8 bfr = *(const short8*)(Wt + (size_t)(j0 + 16 * t + ln) * D_ + kc * 32 + 8 * lg);
            acc[t] = __builtin_amdgcn_mfma_f32_16x16x32_bf16(afr, bfr, acc[t], 0, 0, 0);
        }
    }
    if (j0 < 512) {
        unsigned short* dst = (j0 < 256) ? Q : K;
        int jb = (j0 < 256) ? j0 : (j0 - 256);
#pragma unroll
        for (int t = 0; t < 8; ++t)
#pragma unroll
            for (int i = 0; i < 4; ++i)
                dst[(size_t)(i0 + lg * 4 + i) * U_ + jb + 16 * t + ln] = f2bf(acc[t][i]);
    } else {
        // V: transpose through LDS, coalesced Vt stores
#pragma unroll
        for (int t = 0; t < 8; ++t) {
            int u = 16 * t + ln;
#pragma unroll
            for (int i = 0; i < 4; ++i)
                ldsT[u][w * 16 + lg * 4 + i] = (short)f2bf(acc[t][i]);
        }
        __syncthreads();
        int u = threadIdx.x >> 1, half = threadIdx.x & 1;
        int vrow = j0 - 512 + u;
        int cb = blockIdx.x * 64 + half * 32;
#pragma unroll
        for (int s2 = 0; s2 < 4; ++s2) {
            short8 v = *(const short8*)(&ldsT[u][half * 32 + s2 * 8]);
            *(short8*)(Vt + (size_t)vrow * N_ + cb + s2 * 8) = v;
        }
    }
}

// ---------------- kernel 2: flash attention partials ----------------
// grid (128, 8): blockIdx.x -> 64 Q rows (4 waves x 16), blockIdx.y -> KV slice (1024 rows).
__global__ __launch_bounds__(256, 3) void k_attn(const unsigned short* __restrict__ Q,
        const unsigned short* __restrict__ K, const unsigned short* __restrict__ Vt,
        unsigned short* __restrict__ Opart, float* __restrict__ ml, int jlen) {
    __shared__ __align__(16) char ldsK[16384];   // [32 rows][512 B], byte ^= (row&7)<<4
    __shared__ __align__(16) char ldsV[20480];   // [256 u][80 B pad]  (64 B data)
    __shared__ __align__(16) char ldsP[5120];    // 4 waves x [16 rows][80 B pad] (64 B data)

    const int tid = threadIdx.x;
    const int w = tid >> 6, l = tid & 63, lg = l >> 4, ln = l & 15;
    const int q0 = blockIdx.x * 64 + w * 16;
    const int sp = blockIdx.y;
    const int jbase = sp * jlen;

    short8 qf[8];
#pragma unroll
    for (int kc = 0; kc < 8; ++kc)
        qf[kc] = *(const short8*)(Q + (size_t)(q0 + ln) * U_ + kc * 32 + 8 * lg);

    f32x4 acc[16] = {};
    float mrun[4], lsum[4];
#pragma unroll
    for (int i = 0; i < 4; ++i) { mrun[i] = -3.0e38f; lsum[i] = 0.f; }

    for (int it = 0; it < jlen / 32; ++it) {
        const int j0 = jbase + it * 32;
        __syncthreads();
        // ---- stage K tile [32][512B]
        {
            const char* gK = (const char*)K + (size_t)j0 * 512;
#pragma unroll
            for (int r = 0; r < 4; ++r) {
                int o = (r * 256 + tid) * 16;
                u32x4 v = *(const u32x4*)(gK + o);
                int row = o >> 9;
                *(u32x4*)(ldsK + (o ^ ((row & 7) << 4))) = v;
            }
            const char* gV = (const char*)Vt + (size_t)j0 * 2;
#pragma unroll
            for (int r = 0; r < 4; ++r) {
                int o = (r * 256 + tid) * 16;
                int u = o >> 6, colb = o & 63;
                u32x4 v = *(const u32x4*)(gV + (size_t)u * (N_ * 2) + colb);
                *(u32x4*)(ldsV + u * 80 + colb) = v;
            }
        }
        __syncthreads();

        // ---- S = Q K^T : two 16x16 col-tiles (scale pre-folded into Wq)
        f32x4 s0 = {}, s1 = {};
#pragma unroll
        for (int kc = 0; kc < 8; ++kc) {
            int colb = kc * 64 + lg * 16;
            int r0 = ln, r1 = 16 + ln;
            short8 b0 = *(const short8*)(ldsK + r0 * 512 + (colb ^ ((r0 & 7) << 4)));
            short8 b1 = *(const short8*)(ldsK + r1 * 512 + (colb ^ ((r1 & 7) << 4)));
            s0 = __builtin_amdgcn_mfma_f32_16x16x32_bf16(qf[kc], b0, s0, 0, 0, 0);
            s1 = __builtin_amdgcn_mfma_f32_16x16x32_bf16(qf[kc], b1, s1, 0, 0, 0);
        }

        // ---- online softmax: deferred rescale (THR=2, exact math), per-lane lsum
        int need = 0;
        float mxl[4];
#pragma unroll
        for (int i = 0; i < 4; ++i) {
            mxl[i] = fmaxf(s0[i], s1[i]);
            need |= (mxl[i] > mrun[i] + 2.0f);
        }
        if (__any(need)) {
#pragma unroll
            for (int i = 0; i < 4; ++i) {
                float mx = mxl[i];
#pragma unroll
                for (int off = 1; off < 16; off <<= 1)
                    mx = fmaxf(mx, __shfl_xor(mx, off, 64));
                float mn = fmaxf(mrun[i], mx);
                float al = __expf(mrun[i] - mn);
                mrun[i] = mn;
                lsum[i] *= al;
#pragma unroll
                for (int t = 0; t < 16; ++t) acc[t][i] *= al;
            }
        }
        char* pb = ldsP + w * 1280;
#pragma unroll
        for (int i = 0; i < 4; ++i) {
            float e0 = __expf(s0[i] - mrun[i]);
            float e1 = __expf(s1[i] - mrun[i]);
            lsum[i] += e0 + e1;
            int row = lg * 4 + i;
            *(short*)(pb + row * 80 + ln * 2)      = (short)f2bf(e0);
            *(short*)(pb + row * 80 + 32 + ln * 2) = (short)f2bf(e1);
        }
        asm volatile("s_waitcnt lgkmcnt(0)" ::: "memory");
        __builtin_amdgcn_sched_barrier(0);
        short8 pa = *(const short8*)(pb + ln * 80 + lg * 16);

        // ---- O += P @ V  (16 u-tiles)
#pragma unroll
        for (int t = 0; t < 16; ++t) {
            int u = t * 16 + ln;
            short8 bv = *(const short8*)(ldsV + u * 80 + lg * 16);
            acc[t] = __builtin_amdgcn_mfma_f32_16x16x32_bf16(pa, bv, acc[t], 0, 0, 0);
        }
    }

    // ---- write partials (bf16) + (m, l)
    unsigned short* Op = Opart + (size_t)sp * N_ * U_;
#pragma unroll
    for (int t = 0; t < 16; ++t) {
        int u = t * 16 + ln;
#pragma unroll
        for (int i = 0; i < 4; ++i)
            Op[(size_t)(q0 + lg * 4 + i) * U_ + u] = f2bf(acc[t][i]);
    }
#pragma unroll
    for (int i = 0; i < 4; ++i) {
        float rs = lsum[i];
#pragma unroll
        for (int off = 1; off < 16; off <<= 1)
            rs += __shfl_xor(rs, off, 64);
        if (ln == 0) {
            int row = q0 + lg * 4 + i;
            ml[(size_t)sp * 2 * N_ + row]      = mrun[i];
            ml[(size_t)sp * 2 * N_ + N_ + row] = rs;
        }
    }
}

// ---------------- kernel 3: combine 8 KV-splits -> PV bf16 ----------------
__global__ void k_combine(const unsigned short* __restrict__ Opart, const float* __restrict__ ml,
                          unsigned short* __restrict__ PV, int nsplit) {
    int idx = blockIdx.x * 256 + threadIdx.x;      // one thread = 4 u's of one row
    int row = idx >> 6;
    int u4  = (idx & 63) * 4;
    float m = -3.0e38f;
    for (int sp = 0; sp < nsplit; ++sp)
        m = fmaxf(m, ml[(size_t)sp * 2 * N_ + row]);
    float a0 = 0.f, a1 = 0.f, a2 = 0.f, a3 = 0.f, lsum = 0.f;
    for (int sp = 0; sp < nsplit; ++sp) {
        float ms = ml[(size_t)sp * 2 * N_ + row];
        float ls = ml[(size_t)sp * 2 * N_ + N_ + row];
        float a = __expf(ms - m);
        lsum += ls * a;
        u32x2 pk = *(const u32x2*)(Opart + (size_t)sp * N_ * U_ + (size_t)row * U_ + u4);
        a0 += bf2f((unsigned short)(pk[0] & 0xffffu)) * a;
        a1 += bf2f((unsigned short)(pk[0] >> 16)) * a;
        a2 += bf2f((unsigned short)(pk[1] & 0xffffu)) * a;
        a3 += bf2f((unsigned short)(pk[1] >> 16)) * a;
    }
    float inv = 1.0f / lsum;
    unsigned int lo = (unsigned int)f2bf(a0 * inv) | ((unsigned int)f2bf(a1 * inv) << 16);
    unsigned int hi = (unsigned int)f2bf(a2 * inv) | ((unsigned int)f2bf(a3 * inv) << 16);
    u32x2 pk; pk[0] = lo; pk[1] = hi;
    *(u32x2*)(PV + (size_t)row * U_ + u4) = pk;
}

// ---------------- kernel 4: out = PV @ Wo, 64x128 tiles ----------------
__global__ __launch_bounds__(256) void k_out(const unsigned short* __restrict__ PV,
        const unsigned short* __restrict__ Wot, float* __restrict__ out) {
    const int w = threadIdx.x >> 6, l = threadIdx.x & 63;
    const int lg = l >> 4, ln = l & 15;
    const int i0 = blockIdx.x * 64 + w * 16;
    const int j0 = blockIdx.y * 128;
    f32x4 acc[8] = {};
#pragma unroll
    for (int kc = 0; kc < 8; ++kc) {
        short8 afr = *(const short8*)(PV + (size_t)(i0 + ln) * U_ + kc * 32 + 8 * lg);
#pragma unroll
        for (int t = 0; t < 8; ++t) {
            short8 bfr = *(const short8*)(Wot + (size_t)(j0 + 16 * t + ln) * U_ + kc * 32 + 8 * lg);
            acc[t] = __builtin_amdgcn_mfma_f32_16x16x32_bf16(afr, bfr, acc[t], 0, 0, 0);
        }
    }
#pragma unroll
    for (int t = 0; t < 8; ++t)
#pragma unroll
        for (int i = 0; i < 4; ++i)
            out[(size_t)(i0 + lg * 4 + i) * D_ + j0 + 16 * t + ln] = acc[t][i];
}

// ---------------- launch ----------------
extern "C" void kernel_launch(void* const* d_in, const int* in_sizes, int n_in,
                              void* d_out, int out_size, void* d_ws, size_t ws_size,
                              hipStream_t stream) {
    const float* x  = (const float*)d_in[0];
    const float* Wq = (const float*)d_in[1];
    const float* Wk = (const float*)d_in[2];
    const float* Wv = (const float*)d_in[3];
    const float* Wo = (const float*)d_in[4];
    float* out = (float*)d_out;

    char* ws = (char*)d_ws;
    unsigned short* Wt    = (unsigned short*)(ws);                 // 786432 B
    unsigned short* Wot   = (unsigned short*)(ws + 786432);        // 262144 B
    unsigned short* xb    = (unsigned short*)(ws + 1048576);       // 8 MiB
    unsigned short* Q     = (unsigned short*)(ws + 9437184);       // 4 MiB
    unsigned short* K     = (unsigned short*)(ws + 13631488);      // 4 MiB
    unsigned short* Vt    = (unsigned short*)(ws + 17825792);      // 4 MiB (transposed)
    unsigned short* PV    = (unsigned short*)(ws + 22020096);      // 4 MiB
    unsigned short* Opart = (unsigned short*)(ws + 26214400);      // 8 x 4 MiB (bf16)
    float*          mlp   = (float*)(ws + 59768832);               // 8 x 64 KiB
    (void)in_sizes; (void)n_in; (void)out_size; (void)ws_size;

    const int nsplit = 8;
    k_convert<<<18432, 256, 0, stream>>>(x, Wq, Wk, Wv, Wo, Wt, Wot, xb);
    k_qkv<<<dim3(128, 6), 256, 0, stream>>>(xb, Wt, Q, K, Vt);
    k_attn<<<dim3(128, nsplit), 256, 0, stream>>>(Q, K, Vt, Opart, mlp, N_ / nsplit);
    k_combine<<<2048, 256, 0, stream>>>(Opart, mlp, PV, nsplit);
    k_out<<<dim3(128, 4), 256, 0, stream>>>(PV, Wot, out);
}

// Round 4
// 197.761 us; speedup vs baseline: 2.0398x; 1.4761x over previous
//
#include <hip/hip_runtime.h>
#include <stdint.h>

// FeatureAttention: N=8192, D=512, U=256, fp32 in/out.
// out = softmax((xWq/16)(xWk)^T) (xWv) Wo
// k_attn: 32x32x16 bf16 MFMA, swapped QK^T (S^T = K x Q), in-register softmax
// via cvt_pk_bf16 + permlane32_swap, KV-split=8, XCD-local KV slices.
// Fragment layouts (32x32x16): A: lane l holds A[l&31][8*(l>>5)+e]
//                              B: lane l holds B[8*(l>>5)+e][l&31]
//                              C/D: reg r -> row (r&3)+8*(r>>2)+4*(l>>5), col l&31

#define N_ 8192
#define D_ 512
#define U_ 256

typedef __attribute__((ext_vector_type(8))) short short8;
typedef __attribute__((ext_vector_type(4))) float f32x4;
typedef __attribute__((ext_vector_type(16))) float f32x16;
typedef __attribute__((ext_vector_type(4))) unsigned int u32x4;
typedef __attribute__((ext_vector_type(2))) unsigned int u32x2;
typedef __attribute__((ext_vector_type(2))) unsigned int uint2v;

static __device__ __forceinline__ unsigned short f2bf(float f) {
    union { float f; unsigned int u; } c; c.f = f;
    unsigned int u = c.u;
    u += 0x7FFFu + ((u >> 16) & 1u);   // RNE
    return (unsigned short)(u >> 16);
}
static __device__ __forceinline__ float bf2f(unsigned int h) {
    union { unsigned int u; float f; } c; c.u = h << 16;
    return c.f;
}
static __device__ __forceinline__ unsigned int cvtpk(float lo, float hi) {
    unsigned int d;
    asm("v_cvt_pk_bf16_f32 %0, %1, %2" : "=v"(d) : "v"(lo), "v"(hi));
    return d;
}

// ---------------- kernel 0: weight convert (+scale fold) + x->bf16 ----------------
__global__ void k_convert(const float* __restrict__ x, const float* __restrict__ Wq,
                          const float* __restrict__ Wk, const float* __restrict__ Wv,
                          const float* __restrict__ Wo,
                          unsigned short* __restrict__ Wt, unsigned short* __restrict__ Wot,
                          unsigned short* __restrict__ xb) {
    int idx = blockIdx.x * 256 + threadIdx.x;
    const int nWt = 768 * 512;
    const int nWot = 512 * 256;
    if (idx < nWt) {
        int j = idx >> 9, d = idx & 511;
        int which = j >> 8, u = j & 255;
        const float* W = (which == 0) ? Wq : ((which == 1) ? Wk : Wv);
        float v = W[d * 256 + u];
        if (which == 0) v *= 0.0625f;
        Wt[idx] = f2bf(v);
    } else if (idx < nWt + nWot) {
        int i2 = idx - nWt;
        int jj = i2 >> 8, u = i2 & 255;
        Wot[i2] = f2bf(Wo[u * 512 + jj]);
    } else {
        int i3 = idx - (nWt + nWot);
        if (i3 < N_ * D_) xb[i3] = f2bf(x[i3]);
    }
}

// ---------------- kernel 1: QKV = xb @ [Wq|Wk|Wv], 64x128 tiles ----------------
__global__ __launch_bounds__(256) void k_qkv(const unsigned short* __restrict__ xb,
        const unsigned short* __restrict__ Wt,
        unsigned short* __restrict__ Q, unsigned short* __restrict__ K,
        unsigned short* __restrict__ Vt) {
    __shared__ short ldsT[128][72];
    const int w  = threadIdx.x >> 6;
    const int l  = threadIdx.x & 63;
    const int lg = l >> 4, ln = l & 15;
    const int i0 = blockIdx.x * 64 + w * 16;
    const int j0 = blockIdx.y * 128;

    f32x4 acc[8] = {};
#pragma unroll 2
    for (int kc = 0; kc < 16; ++kc) {
        short8 afr = *(const short8*)(xb + (size_t)(i0 + ln) * D_ + kc * 32 + 8 * lg);
#pragma unroll
        for (int t = 0; t < 8; ++t) {
            short8 bfr = *(const short8*)(Wt + (size_t)(j0 + 16 * t + ln) * D_ + kc * 32 + 8 * lg);
            acc[t] = __builtin_amdgcn_mfma_f32_16x16x32_bf16(afr, bfr, acc[t], 0, 0, 0);
        }
    }
    if (j0 < 512) {
        unsigned short* dst = (j0 < 256) ? Q : K;
        int jb = (j0 < 256) ? j0 : (j0 - 256);
#pragma unroll
        for (int t = 0; t < 8; ++t)
#pragma unroll
            for (int i = 0; i < 4; ++i)
                dst[(size_t)(i0 + lg * 4 + i) * U_ + jb + 16 * t + ln] = f2bf(acc[t][i]);
    } else {
#pragma unroll
        for (int t = 0; t < 8; ++t) {
            int u = 16 * t + ln;
#pragma unroll
            for (int i = 0; i < 4; ++i)
                ldsT[u][w * 16 + lg * 4 + i] = (short)f2bf(acc[t][i]);
        }
        __syncthreads();
        int u = threadIdx.x >> 1, half = threadIdx.x & 1;
        int vrow = j0 - 512 + u;
        int cb = blockIdx.x * 64 + half * 32;
#pragma unroll
        for (int s2 = 0; s2 < 4; ++s2) {
            short8 v = *(const short8*)(&ldsT[u][half * 32 + s2 * 8]);
            *(short8*)(Vt + (size_t)vrow * N_ + cb + s2 * 8) = v;
        }
    }
}

// ---------------- kernel 2: flash attention partials (32x32 MFMA) ----------------
// grid 512: sp = b&7 (XCD-local KV slice of 1024 rows), bx = b>>3 -> 128 Q rows.
// 4 waves x 32 Q-rows. Per iter: 32 K-rows.
__global__ __launch_bounds__(256, 2) void k_attn(const unsigned short* __restrict__ Qm,
        const unsigned short* __restrict__ Km, const unsigned short* __restrict__ Vt,
        unsigned short* __restrict__ Opart, float* __restrict__ ml) {
    __shared__ __align__(16) char ldsK[2][16384];  // [32 j][32 slots of 16B], slot^=(j&15)
    __shared__ __align__(16) char ldsV[2][16384];  // [4 jchunk][256 u][16B]
    __shared__ float ldsA[4][32];

    const int tid = threadIdx.x;
    const int w = tid >> 6, l = tid & 63;
    const int j31 = l & 31, hi = l >> 5;
    const int sp = blockIdx.x & 7;
    const int bx = blockIdx.x >> 3;
    const int q0w = bx * 128 + w * 32;
    const int jbase = sp * 1024;

    // Q fragments (B-operand of swapped QK^T): qf[ks] = Q[q0w+j31][ks*16 + hi*8 + e]
    short8 qf[16];
#pragma unroll
    for (int ks = 0; ks < 16; ++ks)
        qf[ks] = *(const short8*)(Qm + (size_t)(q0w + j31) * U_ + ks * 16 + hi * 8);

    f32x16 acc[8] = {};
    float mrun = -3.0e38f, lsum = 0.f;

    // addressing helpers
    const int kbase = j31 * 512 + ((hi ^ (j31 & 1)) << 4);
    const int kxor = (j31 >> 1) & 7;
    const int vbase = hi * 4096 + j31 * 16;
    const int sK = tid & 31, rK = tid >> 5;      // K staging: slot, row-oct
    const int cV = tid & 3, uV = tid >> 2;       // V staging

    // ---- prologue: stage tile 0 into buf 0
    {
        const char* gK = (const char*)Km + (size_t)jbase * 512;
#pragma unroll
        for (int r = 0; r < 4; ++r) {
            int row = r * 8 + rK;
            const char* src = gK + row * 512 + ((sK ^ (row & 15)) << 4);
            char* dst = &ldsK[0][(row * 32 + sK) * 16];
            __builtin_amdgcn_global_load_lds((const __attribute__((address_space(1))) void*)src,
                                             (__attribute__((address_space(3))) void*)dst, 16, 0, 0);
        }
        const char* gV = (const char*)Vt + (size_t)jbase * 2;
        u32x4 rv0 = *(const u32x4*)(gV + (size_t)(uV +   0) * 16384 + cV * 16);
        u32x4 rv1 = *(const u32x4*)(gV + (size_t)(uV +  64) * 16384 + cV * 16);
        u32x4 rv2 = *(const u32x4*)(gV + (size_t)(uV + 128) * 16384 + cV * 16);
        u32x4 rv3 = *(const u32x4*)(gV + (size_t)(uV + 192) * 16384 + cV * 16);
        char* lv = &ldsV[0][cV * 4096];
        *(u32x4*)(lv + (uV +   0) * 16) = rv0;
        *(u32x4*)(lv + (uV +  64) * 16) = rv1;
        *(u32x4*)(lv + (uV + 128) * 16) = rv2;
        *(u32x4*)(lv + (uV + 192) * 16) = rv3;
    }

    for (int it = 0; it < 32; ++it) {
        const int buf = it & 1, nb = buf ^ 1;
        __syncthreads();

        // ---- issue next-tile staging (T14: issue early, write late)
        u32x4 rv0, rv1, rv2, rv3;
        const bool more = (it + 1 < 32);
        if (more) {
            const int j1 = jbase + (it + 1) * 32;
            const char* gK = (const char*)Km + (size_t)j1 * 512;
#pragma unroll
            for (int r = 0; r < 4; ++r) {
                int row = r * 8 + rK;
                const char* src = gK + row * 512 + ((sK ^ (row & 15)) << 4);
                char* dst = &ldsK[nb][(row * 32 + sK) * 16];
                __builtin_amdgcn_global_load_lds((const __attribute__((address_space(1))) void*)src,
                                                 (__attribute__((address_space(3))) void*)dst, 16, 0, 0);
            }
            const char* gV = (const char*)Vt + (size_t)j1 * 2;
            rv0 = *(const u32x4*)(gV + (size_t)(uV +   0) * 16384 + cV * 16);
            rv1 = *(const u32x4*)(gV + (size_t)(uV +  64) * 16384 + cV * 16);
            rv2 = *(const u32x4*)(gV + (size_t)(uV + 128) * 16384 + cV * 16);
            rv3 = *(const u32x4*)(gV + (size_t)(uV + 192) * 16384 + cV * 16);
        }

        // ---- S^T = K x Q : one 32x32 tile per wave, K-dim 256
        f32x16 sc = {};
        const char* kb = ldsK[buf] + kbase;
        __builtin_amdgcn_s_setprio(1);
#pragma unroll
        for (int ks = 0; ks < 16; ++ks) {
            short8 kf = *(const short8*)(kb + ((ks ^ kxor) << 5));
            sc = __builtin_amdgcn_mfma_f32_32x32x16_bf16(kf, qf[ks], sc, 0, 0, 0);
        }
        __builtin_amdgcn_s_setprio(0);

        // ---- softmax: lane owns S[q=j31][16 j's], deferred rescale (exact, THR=2)
        float t0 = fmaxf(fmaxf(fmaxf(sc[0], sc[1]), fmaxf(sc[2], sc[3])),
                         fmaxf(fmaxf(sc[4], sc[5]), fmaxf(sc[6], sc[7])));
        float t1 = fmaxf(fmaxf(fmaxf(sc[8], sc[9]), fmaxf(sc[10], sc[11])),
                         fmaxf(fmaxf(sc[12], sc[13]), fmaxf(sc[14], sc[15])));
        float tmax = fmaxf(t0, t1);
        tmax = fmaxf(tmax, __shfl_xor(tmax, 32, 64));
        int need = (tmax > mrun + 2.0f);
        if (__any(need)) {
            float mnew = fmaxf(mrun, tmax);
            float al = __expf(mrun - mnew);
            mrun = mnew;
            lsum *= al;
            if (l < 32) ldsA[w][l] = al;
            asm volatile("s_waitcnt lgkmcnt(0)" ::: "memory");
            __builtin_amdgcn_sched_barrier(0);
#pragma unroll
            for (int t4 = 0; t4 < 4; ++t4) {
                f32x4 av = *(const f32x4*)&ldsA[w][t4 * 8 + hi * 4];
#pragma unroll
                for (int ut = 0; ut < 8; ++ut) {
                    acc[ut][4 * t4 + 0] *= av[0];
                    acc[ut][4 * t4 + 1] *= av[1];
                    acc[ut][4 * t4 + 2] *= av[2];
                    acc[ut][4 * t4 + 3] *= av[3];
                }
            }
        }
#pragma unroll
        for (int r = 0; r < 16; ++r) sc[r] = __expf(sc[r] - mrun);
        lsum += ((sc[0] + sc[1]) + (sc[2] + sc[3])) + ((sc[4] + sc[5]) + (sc[6] + sc[7]))
              + ((sc[8] + sc[9]) + (sc[10] + sc[11])) + ((sc[12] + sc[13]) + (sc[14] + sc[15]));

        // ---- P -> bf16 A-frags in-register (cvt_pk + permlane32_swap)
        unsigned int pk0 = cvtpk(sc[0], sc[1]),  pk1 = cvtpk(sc[2], sc[3]);
        unsigned int pk2 = cvtpk(sc[4], sc[5]),  pk3 = cvtpk(sc[6], sc[7]);
        unsigned int pk4 = cvtpk(sc[8], sc[9]),  pk5 = cvtpk(sc[10], sc[11]);
        unsigned int pk6 = cvtpk(sc[12], sc[13]), pk7 = cvtpk(sc[14], sc[15]);
        uint2v r02 = __builtin_amdgcn_permlane32_swap(pk0, pk2, false, false);
        uint2v r13 = __builtin_amdgcn_permlane32_swap(pk1, pk3, false, false);
        uint2v r46 = __builtin_amdgcn_permlane32_swap(pk4, pk6, false, false);
        uint2v r57 = __builtin_amdgcn_permlane32_swap(pk5, pk7, false, false);
        union { u32x4 u; short8 s; } fa0, fa1;
        fa0.u[0] = r02[0]; fa0.u[1] = r13[0]; fa0.u[2] = r02[1]; fa0.u[3] = r13[1];
        fa1.u[0] = r46[0]; fa1.u[1] = r57[0]; fa1.u[2] = r46[1]; fa1.u[3] = r57[1];

        // ---- write V staging (loads issued before QK^T have had ~300+ cy)
        if (more) {
            char* lv = &ldsV[nb][cV * 4096];
            *(u32x4*)(lv + (uV +   0) * 16) = rv0;
            *(u32x4*)(lv + (uV +  64) * 16) = rv1;
            *(u32x4*)(lv + (uV + 128) * 16) = rv2;
            *(u32x4*)(lv + (uV + 192) * 16) = rv3;
        }

        // ---- O += P @ V : 8 u-tiles x 2 k-steps
        const char* vb = ldsV[buf] + vbase;
        __builtin_amdgcn_s_setprio(1);
#pragma unroll
        for (int ut = 0; ut < 8; ++ut) {
            short8 b0 = *(const short8*)(vb + ut * 512);
            short8 b1 = *(const short8*)(vb + 8192 + ut * 512);
            acc[ut] = __builtin_amdgcn_mfma_f32_32x32x16_bf16(fa0.s, b0, acc[ut], 0, 0, 0);
            acc[ut] = __builtin_amdgcn_mfma_f32_32x32x16_bf16(fa1.s, b1, acc[ut], 0, 0, 0);
        }
        __builtin_amdgcn_s_setprio(0);
    }

    // ---- epilogue: unnormalized O (bf16, flat layout) + (m, l)
    float ltot = lsum + __shfl_xor(lsum, 32, 64);
    if (l < 32) {
        int row = q0w + l;
        ml[(size_t)sp * 2 * N_ + row]      = mrun;
        ml[(size_t)sp * 2 * N_ + N_ + row] = ltot;
    }
    unsigned int* Op32 = (unsigned int*)(Opart + (size_t)sp * N_ * U_);
    const int unit = bx * 4 + w;
#pragma unroll
    for (int ut = 0; ut < 8; ++ut) {
        unsigned int o[8];
#pragma unroll
        for (int t = 0; t < 8; ++t) o[t] = cvtpk(acc[ut][2 * t], acc[ut][2 * t + 1]);
        unsigned int* dst = Op32 + (size_t)(unit * 4096 + ut * 512 + l * 8);
        *(u32x4*)(dst)     = *(u32x4*)&o[0];
        *(u32x4*)(dst + 4) = *(u32x4*)&o[4];
    }
}

// ---------------- kernel 3: combine 8 KV-splits -> PV bf16 (row-major) ----------------
__global__ __launch_bounds__(256) void k_combine(const unsigned short* __restrict__ Opart,
        const float* __restrict__ ml, unsigned short* __restrict__ PV) {
    __shared__ float tile[32][260];
    __shared__ float Arow[8][32];
    __shared__ float Linv[32];
    const int t = threadIdx.x, unit = blockIdx.x;
    const int q0 = unit * 32;
    if (t < 32) {
        float m = -3.0e38f;
#pragma unroll
        for (int sp = 0; sp < 8; ++sp) m = fmaxf(m, ml[(size_t)sp * 2 * N_ + q0 + t]);
        float L = 0.f;
#pragma unroll
        for (int sp = 0; sp < 8; ++sp) {
            float a = __expf(ml[(size_t)sp * 2 * N_ + q0 + t] - m);
            Arow[sp][t] = a;
            L += ml[(size_t)sp * 2 * N_ + N_ + q0 + t] * a;
        }
        Linv[t] = 1.0f / L;
    }
    __syncthreads();

    const int qb = 8 * (t & 3) + 4 * (t >> 7);     // q' base for this thread's 4 rows
    const int lane = t >> 2;
    float a0[8], a1[8], a2[8], a3[8];
#pragma unroll
    for (int it = 0; it < 8; ++it) { a0[it] = 0.f; a1[it] = 0.f; a2[it] = 0.f; a3[it] = 0.f; }
    const unsigned int* Ob = (const unsigned int*)Opart;
#pragma unroll
    for (int sp = 0; sp < 8; ++sp) {
        const unsigned int* base = Ob + (size_t)sp * (N_ * U_ / 2) + unit * 4096;
        float w0 = Arow[sp][qb], w1 = Arow[sp][qb + 1], w2 = Arow[sp][qb + 2], w3 = Arow[sp][qb + 3];
#pragma unroll
        for (int it = 0; it < 8; ++it) {
            u32x2 pk = *(const u32x2*)(base + it * 512 + t * 2);
            a0[it] += bf2f(pk[0] & 0xffffu) * w0;
            a1[it] += bf2f(pk[0] >> 16) * w1;
            a2[it] += bf2f(pk[1] & 0xffffu) * w2;
            a3[it] += bf2f(pk[1] >> 16) * w3;
        }
    }
#pragma unroll
    for (int it = 0; it < 8; ++it) {
        int u = it * 32 + (lane & 31);
        tile[qb + 0][u] = a0[it];
        tile[qb + 1][u] = a1[it];
        tile[qb + 2][u] = a2[it];
        tile[qb + 3][u] = a3[it];
    }
    __syncthreads();

    const int row = t >> 3, c8 = t & 7;
    float li = Linv[row];
    unsigned int opk[16];
#pragma unroll
    for (int k2 = 0; k2 < 16; ++k2) {
        float lo = tile[row][c8 * 32 + 2 * k2] * li;
        float hhi = tile[row][c8 * 32 + 2 * k2 + 1] * li;
        opk[k2] = (unsigned int)f2bf(lo) | ((unsigned int)f2bf(hhi) << 16);
    }
    unsigned int* dst = (unsigned int*)(PV + (size_t)(q0 + row) * U_ + c8 * 32);
    *(u32x4*)(dst + 0)  = *(u32x4*)&opk[0];
    *(u32x4*)(dst + 4)  = *(u32x4*)&opk[4];
    *(u32x4*)(dst + 8)  = *(u32x4*)&opk[8];
    *(u32x4*)(dst + 12) = *(u32x4*)&opk[12];
}

// ---------------- kernel 4: out = PV @ Wo, 64x128 tiles ----------------
__global__ __launch_bounds__(256) void k_out(const unsigned short* __restrict__ PV,
        const unsigned short* __restrict__ Wot, float* __restrict__ out) {
    const int w = threadIdx.x >> 6, l = threadIdx.x & 63;
    const int lg = l >> 4, ln = l & 15;
    const int i0 = blockIdx.x * 64 + w * 16;
    const int j0 = blockIdx.y * 128;
    f32x4 acc[8] = {};
#pragma unroll
    for (int kc = 0; kc < 8; ++kc) {
        short8 afr = *(const short8*)(PV + (size_t)(i0 + ln) * U_ + kc * 32 + 8 * lg);
#pragma unroll
        for (int t = 0; t < 8; ++t) {
            short8 bfr = *(const short8*)(Wot + (size_t)(j0 + 16 * t + ln) * U_ + kc * 32 + 8 * lg);
            acc[t] = __builtin_amdgcn_mfma_f32_16x16x32_bf16(afr, bfr, acc[t], 0, 0, 0);
        }
    }
#pragma unroll
    for (int t = 0; t < 8; ++t)
#pragma unroll
        for (int i = 0; i < 4; ++i)
            out[(size_t)(i0 + lg * 4 + i) * D_ + j0 + 16 * t + ln] = acc[t][i];
}

// ---------------- launch ----------------
extern "C" void kernel_launch(void* const* d_in, const int* in_sizes, int n_in,
                              void* d_out, int out_size, void* d_ws, size_t ws_size,
                              hipStream_t stream) {
    const float* x  = (const float*)d_in[0];
    const float* Wq = (const float*)d_in[1];
    const float* Wk = (const float*)d_in[2];
    const float* Wv = (const float*)d_in[3];
    const float* Wo = (const float*)d_in[4];
    float* out = (float*)d_out;

    char* ws = (char*)d_ws;
    unsigned short* Wt    = (unsigned short*)(ws);                 // 786432 B
    unsigned short* Wot   = (unsigned short*)(ws + 786432);        // 262144 B
    unsigned short* xb    = (unsigned short*)(ws + 1048576);       // 8 MiB
    unsigned short* Q     = (unsigned short*)(ws + 9437184);       // 4 MiB
    unsigned short* K     = (unsigned short*)(ws + 13631488);      // 4 MiB
    unsigned short* Vt    = (unsigned short*)(ws + 17825792);      // 4 MiB (transposed)
    unsigned short* PV    = (unsigned short*)(ws + 22020096);      // 4 MiB
    unsigned short* Opart = (unsigned short*)(ws + 26214400);      // 8 x 4 MiB (bf16, flat)
    float*          mlp   = (float*)(ws + 59768832);               // 8 x 64 KiB
    (void)in_sizes; (void)n_in; (void)out_size; (void)ws_size;

    k_convert<<<18432, 256, 0, stream>>>(x, Wq, Wk, Wv, Wo, Wt, Wot, xb);
    k_qkv<<<dim3(128, 6), 256, 0, stream>>>(xb, Wt, Q, K, Vt);
    k_attn<<<512, 256, 0, stream>>>(Q, K, Vt, Opart, mlp);
    k_combine<<<256, 256, 0, stream>>>(Opart, mlp, PV);
    k_out<<<dim3(128, 4), 256, 0, stream>>>(PV, Wot, out);
}